// Round 1
// baseline (100.345 us; speedup 1.0000x reference)
//
#include <hip/hip_runtime.h>
#include <stdint.h>

// ---------------------------------------------------------------------------
// VectorAttentionLayerV3: fused bf16-MFMA implementation for MI355X (gfx950)
// B=2, N=16384, M=16, C=64, H=64
//
// Math (after folding BN into the first conv and W1 through Q/K):
//   h   = center@Aq^T - nbr@Ak^T + pos@A1^T + b1      (Ak stored pre-negated)
//   a2  = relu(h) @ W2^T
//   w   = softmax_m(a2)
//   out = sum_m w * (nbr@Wv^T + pos)
// ---------------------------------------------------------------------------

#define NN 16384

typedef float f32x4 __attribute__((ext_vector_type(4)));
typedef short s16x8 __attribute__((ext_vector_type(8)));
typedef int   i32x4 __attribute__((ext_vector_type(4)));
typedef int   i32x2 __attribute__((ext_vector_type(2)));

__device__ __forceinline__ uint16_t f2bf(float f) {
  uint32_t u = __builtin_bit_cast(uint32_t, f);
  u += 0x7fffu + ((u >> 16) & 1u);   // round-to-nearest-even
  return (uint16_t)(u >> 16);
}
__device__ __forceinline__ uint32_t pk2(float a, float b) {
  return (uint32_t)f2bf(a) | ((uint32_t)f2bf(b) << 16);
}

__device__ __forceinline__ f32x4 mma16(i32x4 a, i32x4 b, f32x4 c) {
  return __builtin_amdgcn_mfma_f32_16x16x32_bf16(
      __builtin_bit_cast(s16x8, a), __builtin_bit_cast(s16x8, b), c, 0, 0, 0);
}

// A-fragment from row-major f32: p -> row base + g*4; k-half0 at +0, half1 at +16
__device__ __forceinline__ i32x4 afrag(const float* p) {
  f32x4 f0 = *(const f32x4*)p;
  f32x4 f1 = *(const f32x4*)(p + 16);
  i32x4 r;
  r.x = pk2(f0.x, f0.y); r.y = pk2(f0.z, f0.w);
  r.z = pk2(f1.x, f1.y); r.w = pk2(f1.z, f1.w);
  return r;
}

// ---------------- weight prepass: combine, scale, pack to B-frag layout -----
// Packed layout: wp[((mat*8 + kt*4 + ct)*64 + lane)*8 + e] (bf16), where for
// B[k][j]=W[j][k]: j = 16*ct + (lane&15), k = kt*32 + (e>=4)*16 + 4*(lane>>4) + (e&3)
__device__ __forceinline__ void wstore(uint16_t* wp, int mat, int j, int k, float v) {
  int ct = j >> 4, jl = j & 15;
  int kt = k >> 5, r = k & 31;
  int kh = r >> 4, rr = r & 15;
  int gg = rr >> 2, e2 = rr & 3;
  int lanei = jl + (gg << 4);
  int e = kh * 4 + e2;
  wp[((mat * 8 + kt * 4 + ct) * 64 + lanei) * 8 + e] = f2bf(v);
}

__global__ void prep_weights(const float* __restrict__ Wq, const float* __restrict__ Wkv,
                             const float* __restrict__ W1, const float* __restrict__ gam,
                             const float* __restrict__ bet, const float* __restrict__ mu,
                             const float* __restrict__ var, const float* __restrict__ W2,
                             uint16_t* __restrict__ wp, float* __restrict__ b1) {
  int j = blockIdx.x * 16 + (threadIdx.x >> 4);   // out index 0..63
  int q = threadIdx.x & 15;
  float gp = gam[j] * rsqrtf(var[j] + 1e-5f);
  if (q == 0) b1[j] = bet[j] - gp * mu[j];
  for (int k = q * 4; k < q * 4 + 4; ++k) {
    float aq = 0.f, ak = 0.f;
    for (int c = 0; c < 64; ++c) {
      float w1 = W1[j * 64 + c];
      aq += w1 * Wq[c * 64 + k];     // (W1·Wq)[j][k]
      ak += w1 * Wkv[c * 64 + k];    // (W1·Wk)[j][k]
    }
    wstore(wp, 0, j, k, gp * aq);                 // Aq
    wstore(wp, 1, j, k, -gp * ak);                // -Ak  (pre-negated)
    wstore(wp, 2, j, k, gp * W1[j * 64 + k]);     // A1
    wstore(wp, 3, j, k, Wkv[(64 + j) * 64 + k]);  // Wv
    wstore(wp, 4, j, k, W2[j * 64 + k]);          // W2
  }
}

// ---------------- main fused kernel ----------------------------------------
#define W_LDS_ELEMS (5 * 4096)
#define HSTR 72   // padded bf16 row stride of the h transpose tile (144 B)

__device__ __forceinline__ i32x4 bfragld(const uint16_t* wlds, int mat, int kt, int ct, int lane) {
  return *(const i32x4*)(wlds + ((mat * 8 + kt * 4 + ct) * 64 + lane) * 8);
}

__global__ __launch_bounds__(256, 2) void vattn_main(
    const float* __restrict__ center, const float* __restrict__ nbr,
    const float* __restrict__ pos, const uint16_t* __restrict__ wp,
    const float* __restrict__ b1, float* __restrict__ out) {
  __shared__ uint16_t wlds[W_LDS_ELEMS];
  __shared__ uint16_t hlds[4 * 16 * HSTR];
  const int tid = threadIdx.x;
  {
    const i32x4* src = (const i32x4*)wp;
    i32x4* dst = (i32x4*)wlds;
#pragma unroll
    for (int i = 0; i < 10; ++i) dst[tid + 256 * i] = src[tid + 256 * i];
  }
  __syncthreads();

  const int w = tid >> 6;
  const int lane = tid & 63;
  const int l15 = lane & 15;
  const int g = lane >> 4;
  const int blk = blockIdx.x;
  const int b = blk >> 10;
  const int n0 = (blk & 1023) << 4;
  const long crow0 = (long)b * NN + n0;

  float b1v[4];
#pragma unroll
  for (int ct = 0; ct < 4; ++ct) b1v[ct] = b1[ct * 16 + l15];

  // --- qh tile: all 16 n's of this block (redundant per wave, 8 MFMAs) ---
  f32x4 qh[4];
#pragma unroll
  for (int ct = 0; ct < 4; ++ct) qh[ct] = (f32x4){0.f, 0.f, 0.f, 0.f};
  {
    const float* crow = center + (crow0 + l15) * 64 + g * 4;
    i32x4 ca0 = afrag(crow);
    i32x4 ca1 = afrag(crow + 32);
#pragma unroll
    for (int ct = 0; ct < 4; ++ct) {
      qh[ct] = mma16(ca0, bfragld(wlds, 0, 0, ct, lane), qh[ct]);
      qh[ct] = mma16(ca1, bfragld(wlds, 0, 1, ct, lane), qh[ct]);
      f32x4 bb = {b1v[ct], b1v[ct], b1v[ct], b1v[ct]};
      qh[ct] = qh[ct] + bb;        // fold BN bias in once
    }
  }

  uint16_t* hw = hlds + w * 16 * HSTR;   // per-wave private region

#pragma unroll
  for (int rt = 0; rt < 4; ++rt) {
    const int nl = (w << 2) + rt;        // n within block, 0..15
    const long nrow = crow0 + nl;
    const float* nrp = nbr + (nrow * 16 + l15) * 64 + g * 4;
    const float* prp = pos + (nrow * 16 + l15) * 64 + g * 4;
    i32x4 na0 = afrag(nrp), na1 = afrag(nrp + 32);
    i32x4 pa0 = afrag(prp), pa1 = afrag(prp + 32);

    // broadcast qh[n=nl][col] to all lanes (value lives in lane l15+16*w, reg rt)
    float qb[4];
#pragma unroll
    for (int ct = 0; ct < 4; ++ct) qb[ct] = __shfl(qh[ct][rt], l15 + (w << 4), 64);

    f32x4 hb[4], vv[4];
#pragma unroll
    for (int ct = 0; ct < 4; ++ct) {
      hb[ct] = (f32x4){qb[ct], qb[ct], qb[ct], qb[ct]};
      vv[ct] = (f32x4){0.f, 0.f, 0.f, 0.f};
    }
#pragma unroll
    for (int ct = 0; ct < 4; ++ct) {
      hb[ct] = mma16(na0, bfragld(wlds, 1, 0, ct, lane), hb[ct]);  // -K@W1 (pre-neg)
      hb[ct] = mma16(na1, bfragld(wlds, 1, 1, ct, lane), hb[ct]);
      hb[ct] = mma16(pa0, bfragld(wlds, 2, 0, ct, lane), hb[ct]);  // pos@A1
      hb[ct] = mma16(pa1, bfragld(wlds, 2, 1, ct, lane), hb[ct]);
      vv[ct] = mma16(na0, bfragld(wlds, 3, 0, ct, lane), vv[ct]);  // V
      vv[ct] = mma16(na1, bfragld(wlds, 3, 1, ct, lane), vv[ct]);
    }

    // relu -> bf16 -> LDS (row-major [16 m][64 h], padded stride)
#pragma unroll
    for (int ct = 0; ct < 4; ++ct)
#pragma unroll
      for (int r = 0; r < 4; ++r)
        hw[(4 * g + r) * HSTR + ct * 16 + l15] = f2bf(fmaxf(hb[ct][r], 0.f));
    asm volatile("s_waitcnt lgkmcnt(0)" ::: "memory");

    // re-read as A-frags for the W2 GEMM
    const uint16_t* hr = hw + l15 * HSTR + g * 4;
    i32x4 ha0, ha1;
    {
      i32x2 x = *(const i32x2*)(hr);
      i32x2 y = *(const i32x2*)(hr + 16);
      ha0.x = x.x; ha0.y = x.y; ha0.z = y.x; ha0.w = y.y;
    }
    {
      i32x2 x = *(const i32x2*)(hr + 32);
      i32x2 y = *(const i32x2*)(hr + 48);
      ha1.x = x.x; ha1.y = x.y; ha1.z = y.x; ha1.w = y.y;
    }
    f32x4 a2[4];
#pragma unroll
    for (int ct = 0; ct < 4; ++ct) {
      a2[ct] = (f32x4){0.f, 0.f, 0.f, 0.f};
      a2[ct] = mma16(ha0, bfragld(wlds, 4, 0, ct, lane), a2[ct]);
      a2[ct] = mma16(ha1, bfragld(wlds, 4, 1, ct, lane), a2[ct]);
    }

    // softmax over m (rows) + weighted sum of (V + pos)
    const float* posrow = pos + nrow * 16 * 64;
    float ov[4];
#pragma unroll
    for (int ct = 0; ct < 4; ++ct) {
      f32x4 s = a2[ct];
      float mx = fmaxf(fmaxf(s.x, s.y), fmaxf(s.z, s.w));
      mx = fmaxf(mx, __shfl_xor(mx, 16, 64));
      mx = fmaxf(mx, __shfl_xor(mx, 32, 64));
      float e0 = __expf(s.x - mx), e1 = __expf(s.y - mx);
      float e2 = __expf(s.z - mx), e3 = __expf(s.w - mx);
      float sm = e0 + e1 + e2 + e3;
      sm += __shfl_xor(sm, 16, 64);
      sm += __shfl_xor(sm, 32, 64);
      const float* pp = posrow + (4 * g) * 64 + ct * 16 + l15;  // rows 4g+r (L1-hot)
      float ps = e0 * (vv[ct].x + pp[0])   + e1 * (vv[ct].y + pp[64]) +
                 e2 * (vv[ct].z + pp[128]) + e3 * (vv[ct].w + pp[192]);
      ps += __shfl_xor(ps, 16, 64);
      ps += __shfl_xor(ps, 32, 64);
      ov[ct] = ps / sm;
    }
    float val = (g == 0) ? ov[0] : (g == 1) ? ov[1] : (g == 2) ? ov[2] : ov[3];
    out[nrow * 64 + lane] = val;
  }
}

// ---------------------------------------------------------------------------
extern "C" void kernel_launch(void* const* d_in, const int* in_sizes, int n_in,
                              void* d_out, int out_size, void* d_ws, size_t ws_size,
                              hipStream_t stream) {
  const float* center = (const float*)d_in[0];
  const float* nbr    = (const float*)d_in[1];
  const float* pos    = (const float*)d_in[2];
  const float* Wq     = (const float*)d_in[3];
  const float* Wkv    = (const float*)d_in[4];
  const float* W1     = (const float*)d_in[5];
  const float* gam    = (const float*)d_in[6];
  const float* bet    = (const float*)d_in[7];
  const float* mu     = (const float*)d_in[8];
  const float* var    = (const float*)d_in[9];
  const float* W2     = (const float*)d_in[10];
  uint16_t* wp = (uint16_t*)d_ws;
  float* b1 = (float*)((char*)d_ws + 5 * 4096 * 2);
  prep_weights<<<4, 256, 0, stream>>>(Wq, Wkv, W1, gam, bet, mu, var, W2, wp, b1);
  vattn_main<<<2048, 256, 0, stream>>>(center, nbr, pos, wp, b1, (float*)d_out);
}

// Round 2
// 95.657 us; speedup vs baseline: 1.0490x; 1.0490x over previous
//
#include <hip/hip_runtime.h>
#include <stdint.h>

// ---------------------------------------------------------------------------
// VectorAttentionLayerV3: fused bf16-MFMA implementation for MI355X (gfx950)
// B=2, N=16384, M=16, C=64, H=64
//
// Math (BN folded into conv1, W1 folded through Q/K projections):
//   h   = center@Aq^T - nbr@Ak^T + pos@A1^T + b1      (Ak stored pre-negated)
//   a2  = relu(h) @ W2^T
//   w   = softmax_m(a2)
//   out = sum_m w * (nbr@Wv^T + pos)
//
// R1 restructure: GEMM1 computed transposed (weights as MFMA-A, data as
// MFMA-B) so h^T lands in registers already in A-frag layout for GEMM2 —
// no LDS round-trip, no barriers in the main loop, center folded in as a
// broadcast B operand. Double-buffered global prefetch across the 4 rt's.
// ---------------------------------------------------------------------------

#define NN 16384

typedef float f32x4 __attribute__((ext_vector_type(4)));
typedef short s16x8 __attribute__((ext_vector_type(8)));
typedef int   i32x4 __attribute__((ext_vector_type(4)));

__device__ __forceinline__ uint16_t f2bf(float f) {
  uint32_t u = __builtin_bit_cast(uint32_t, f);
  u += 0x7fffu + ((u >> 16) & 1u);   // round-to-nearest-even
  return (uint16_t)(u >> 16);
}
__device__ __forceinline__ uint32_t pk2(float a, float b) {
  return (uint32_t)f2bf(a) | ((uint32_t)f2bf(b) << 16);
}

__device__ __forceinline__ f32x4 mma16(i32x4 a, i32x4 b, f32x4 c) {
  return __builtin_amdgcn_mfma_f32_16x16x32_bf16(
      __builtin_bit_cast(s16x8, a), __builtin_bit_cast(s16x8, b), c, 0, 0, 0);
}

// pack two f32x4 halves (k 0..3 / k 16..19 pattern) into one bf16 fragment
__device__ __forceinline__ i32x4 packfrag(f32x4 f0, f32x4 f1) {
  i32x4 r;
  r.x = pk2(f0.x, f0.y); r.y = pk2(f0.z, f0.w);
  r.z = pk2(f1.x, f1.y); r.w = pk2(f1.z, f1.w);
  return r;
}
__device__ __forceinline__ i32x4 afrag(const float* p) {
  return packfrag(*(const f32x4*)p, *(const f32x4*)(p + 16));
}

// ---------------- weight prepass: combine, scale, pack to frag layout ------
// Packed layout (works as A-frag via rows or B-frag via cols — same mapping):
// wp[((mat*8 + kt*4 + ct)*64 + lane)*8 + e], where index16 = 16*ct + (lane&15),
// k = kt*32 + (e>=4)*16 + 4*(lane>>4) + (e&3)
__device__ __forceinline__ void wstore(uint16_t* wp, int mat, int j, int k, float v) {
  int ct = j >> 4, jl = j & 15;
  int kt = k >> 5, r = k & 31;
  int kh = r >> 4, rr = r & 15;
  int gg = rr >> 2, e2 = rr & 3;
  int lanei = jl + (gg << 4);
  int e = kh * 4 + e2;
  wp[((mat * 8 + kt * 4 + ct) * 64 + lanei) * 8 + e] = f2bf(v);
}

__global__ void prep_weights(const float* __restrict__ Wq, const float* __restrict__ Wkv,
                             const float* __restrict__ W1, const float* __restrict__ gam,
                             const float* __restrict__ bet, const float* __restrict__ mu,
                             const float* __restrict__ var, const float* __restrict__ W2,
                             uint16_t* __restrict__ wp, float* __restrict__ b1) {
  int j = blockIdx.x * 16 + (threadIdx.x >> 4);   // out index 0..63
  int q = threadIdx.x & 15;
  float gp = gam[j] * rsqrtf(var[j] + 1e-5f);
  if (q == 0) b1[j] = bet[j] - gp * mu[j];
  for (int k = q * 4; k < q * 4 + 4; ++k) {
    float aq = 0.f, ak = 0.f;
    for (int c = 0; c < 64; ++c) {
      float w1 = W1[j * 64 + c];
      aq += w1 * Wq[c * 64 + k];     // (W1·Wq)[j][k]
      ak += w1 * Wkv[c * 64 + k];    // (W1·Wk)[j][k]
    }
    wstore(wp, 0, j, k, gp * aq);                 // Aq   (A-frag rows=ch)
    wstore(wp, 1, j, k, -gp * ak);                // -Ak  (pre-negated)
    wstore(wp, 2, j, k, gp * W1[j * 64 + k]);     // A1
    wstore(wp, 3, j, k, Wkv[(64 + j) * 64 + k]);  // Wv   (B-frag cols=cv)
    wstore(wp, 4, j, k, W2[j * 64 + k]);          // W2   (B-frag cols=c2)
  }
}

// ---------------- main fused kernel ----------------------------------------
#define W_LDS_ELEMS (5 * 4096)   // 40960 B -> 4 blocks/CU LDS ceiling

__device__ __forceinline__ i32x4 bfragld(const uint16_t* wlds, int mat, int kt, int ct, int lane) {
  return *(const i32x4*)(wlds + ((mat * 8 + kt * 4 + ct) * 64 + lane) * 8);
}

__global__ __launch_bounds__(256, 3) void vattn_main(
    const float* __restrict__ center, const float* __restrict__ nbr,
    const float* __restrict__ pos, const uint16_t* __restrict__ wp,
    const float* __restrict__ b1, float* __restrict__ out) {
  __shared__ uint16_t wlds[W_LDS_ELEMS];
  const int tid = threadIdx.x;
  {
    const i32x4* src = (const i32x4*)wp;
    i32x4* dst = (i32x4*)wlds;
#pragma unroll
    for (int i = 0; i < 10; ++i) dst[tid + 256 * i] = src[tid + 256 * i];
  }
  __syncthreads();

  const int w = tid >> 6;
  const int lane = tid & 63;
  const int l15 = lane & 15;
  const int g = lane >> 4;
  const int blk = blockIdx.x;
  const int b = blk >> 10;
  const int n0 = (blk & 1023) << 4;
  const long nbase = (long)b * NN + n0 + (w << 2);   // this wave's first n

  // BN bias as accumulator init: lane holds channels ct*16 + 4g + r
  f32x4 binit[4];
#pragma unroll
  for (int ct = 0; ct < 4; ++ct)
#pragma unroll
    for (int r = 0; r < 4; ++r) binit[ct][r] = b1[ct * 16 + 4 * g + r];

  // double-buffered raw f32 prefetch of nbr + pos fragments
  f32x4 raw[2][8];
#define ISSUE(BUF, RT) do {                                                   \
    const float* nrp_ = nbr + (((nbase + (RT)) * 16 + l15) * 64) + g * 4;     \
    const float* prp_ = pos + (((nbase + (RT)) * 16 + l15) * 64) + g * 4;     \
    raw[BUF][0] = *(const f32x4*)nrp_;        raw[BUF][1] = *(const f32x4*)(nrp_ + 16); \
    raw[BUF][2] = *(const f32x4*)(nrp_ + 32); raw[BUF][3] = *(const f32x4*)(nrp_ + 48); \
    raw[BUF][4] = *(const f32x4*)prp_;        raw[BUF][5] = *(const f32x4*)(prp_ + 16); \
    raw[BUF][6] = *(const f32x4*)(prp_ + 32); raw[BUF][7] = *(const f32x4*)(prp_ + 48); \
  } while (0)

  ISSUE(0, 0);

#pragma unroll
  for (int rt = 0; rt < 4; ++rt) {
    if (rt < 3) ISSUE((rt + 1) & 1, rt + 1);
    const int buf = rt & 1;
    const long nrow = nbase + rt;

    // center fragments (broadcast over lanes' l15 — L1-served)
    const float* crp = center + nrow * 64 + g * 4;
    i32x4 ca0 = afrag(crp), ca1 = afrag(crp + 32);

    // pack current buffer to bf16 fragments (serve as MFMA-B: col=m=l15)
    i32x4 na0 = packfrag(raw[buf][0], raw[buf][1]);
    i32x4 na1 = packfrag(raw[buf][2], raw[buf][3]);
    i32x4 pa0 = packfrag(raw[buf][4], raw[buf][5]);
    i32x4 pa1 = packfrag(raw[buf][6], raw[buf][7]);

    // GEMM1 (transposed): h^T[ch][m], weights as A, data as B. 24 MFMAs.
    f32x4 h[4];
#pragma unroll
    for (int ct = 0; ct < 4; ++ct) {
      h[ct] = binit[ct];
      h[ct] = mma16(bfragld(wlds, 0, 0, ct, lane), ca0, h[ct]);  // Aq · center
      h[ct] = mma16(bfragld(wlds, 0, 1, ct, lane), ca1, h[ct]);
      h[ct] = mma16(bfragld(wlds, 1, 0, ct, lane), na0, h[ct]);  // -Ak · nbr
      h[ct] = mma16(bfragld(wlds, 1, 1, ct, lane), na1, h[ct]);
      h[ct] = mma16(bfragld(wlds, 2, 0, ct, lane), pa0, h[ct]);  // A1 · pos
      h[ct] = mma16(bfragld(wlds, 2, 1, ct, lane), pa1, h[ct]);
    }

    // V GEMM (untransposed): vv[m][cv], data as A, Wv as B. 8 MFMAs.
    f32x4 vv[4];
#pragma unroll
    for (int ct = 0; ct < 4; ++ct) {
      vv[ct] = (f32x4){0.f, 0.f, 0.f, 0.f};
      vv[ct] = mma16(na0, bfragld(wlds, 3, 0, ct, lane), vv[ct]);
      vv[ct] = mma16(na1, bfragld(wlds, 3, 1, ct, lane), vv[ct]);
    }

    // relu + repack: h^T C/D layout IS the A-frag layout for GEMM2
    i32x4 ha0, ha1;
    {
      f32x4 r0, r1, r2, r3;
#pragma unroll
      for (int r = 0; r < 4; ++r) {
        r0[r] = fmaxf(h[0][r], 0.f); r1[r] = fmaxf(h[1][r], 0.f);
        r2[r] = fmaxf(h[2][r], 0.f); r3[r] = fmaxf(h[3][r], 0.f);
      }
      ha0 = packfrag(r0, r1);   // k(ch) 0..31 half
      ha1 = packfrag(r2, r3);   // k(ch) 32..63 half
    }

    // GEMM2 (untransposed): a2[m][c2] = relu(h) @ W2^T. 8 MFMAs.
    f32x4 a2[4];
#pragma unroll
    for (int ct = 0; ct < 4; ++ct) {
      a2[ct] = (f32x4){0.f, 0.f, 0.f, 0.f};
      a2[ct] = mma16(ha0, bfragld(wlds, 4, 0, ct, lane), a2[ct]);
      a2[ct] = mma16(ha1, bfragld(wlds, 4, 1, ct, lane), a2[ct]);
    }

    // softmax over m (rows = 4 regs x 2 lane-group halves) + weighted sum
    const float* posrow = pos + nrow * 16 * 64;
    float ov[4];
#pragma unroll
    for (int ct = 0; ct < 4; ++ct) {
      f32x4 s = a2[ct];
      float mx = fmaxf(fmaxf(s.x, s.y), fmaxf(s.z, s.w));
      mx = fmaxf(mx, __shfl_xor(mx, 16, 64));
      mx = fmaxf(mx, __shfl_xor(mx, 32, 64));
      float e0 = __expf(s.x - mx), e1 = __expf(s.y - mx);
      float e2 = __expf(s.z - mx), e3 = __expf(s.w - mx);
      float sm = e0 + e1 + e2 + e3;
      sm += __shfl_xor(sm, 16, 64);
      sm += __shfl_xor(sm, 32, 64);
      const float* pp = posrow + (4 * g) * 64 + ct * 16 + l15;  // rows 4g+r (L1-hot)
      float ps = e0 * (vv[ct].x + pp[0])   + e1 * (vv[ct].y + pp[64]) +
                 e2 * (vv[ct].z + pp[128]) + e3 * (vv[ct].w + pp[192]);
      ps += __shfl_xor(ps, 16, 64);
      ps += __shfl_xor(ps, 32, 64);
      ov[ct] = ps / sm;
    }
    // lane = l15 + 16g stores channel c2 = 16*g + l15 = lane (coalesced)
    float val = (g == 0) ? ov[0] : (g == 1) ? ov[1] : (g == 2) ? ov[2] : ov[3];
    out[nrow * 64 + lane] = val;
  }
#undef ISSUE
}

// ---------------------------------------------------------------------------
extern "C" void kernel_launch(void* const* d_in, const int* in_sizes, int n_in,
                              void* d_out, int out_size, void* d_ws, size_t ws_size,
                              hipStream_t stream) {
  const float* center = (const float*)d_in[0];
  const float* nbr    = (const float*)d_in[1];
  const float* pos    = (const float*)d_in[2];
  const float* Wq     = (const float*)d_in[3];
  const float* Wkv    = (const float*)d_in[4];
  const float* W1     = (const float*)d_in[5];
  const float* gam    = (const float*)d_in[6];
  const float* bet    = (const float*)d_in[7];
  const float* mu     = (const float*)d_in[8];
  const float* var    = (const float*)d_in[9];
  const float* W2     = (const float*)d_in[10];
  uint16_t* wp = (uint16_t*)d_ws;
  float* b1 = (float*)((char*)d_ws + 5 * 4096 * 2);
  prep_weights<<<4, 256, 0, stream>>>(Wq, Wkv, W1, gam, bet, mu, var, W2, wp, b1);
  vattn_main<<<2048, 256, 0, stream>>>(center, nbr, pos, wp, b1, (float*)d_out);
}